// Round 6
// baseline (388.812 us; speedup 1.0000x reference)
//
#include <hip/hip_runtime.h>
#include <hip/hip_bf16.h>
#include <math.h>

// ---------------------------------------------------------------------------
// MPNN node classifier.
// R18: /256-domain dequant. R17's q8 msg halved gather bytes (388us) but
// VALUBusy hit 47% — 9 int ops per u32 of dequant. The +0x2000 exponent bias
// is unnecessary: bitcast(code<<7) == value/256 exactly for codes >= 8, so
// accumulate raw (2 ops/u32: shl+and, codes<=126 live in bits 7..13) and
// scale the final sum by 256. 33% fewer gather VALU ops. Bonus: code 0 now
// dequants to exactly 0 (denormal), killing the relu-zero +0.0078 bias that
// inflated absmax (16.0) in R17; codes 1-7 err by ~0.007 abs (negligible).
// Producer q8 and byte swizzle {0,2,1,3} unchanged. Pipeline = R17.
// ---------------------------------------------------------------------------

#define F_DIM 256   // F_IN == H == 256
#define C_DIM 40
#define NBUCK 256   // coarse buckets: dst >> 8
#define NB    256   // scatter chunks
#define MAXCHUNK 6400
#define CAP   16384 // fixed packed region per bucket (mean 8192, sigma~90)

typedef _Float16 half8 __attribute__((ext_vector_type(8)));
typedef _Float16 h2    __attribute__((ext_vector_type(2)));
typedef float    f32x4 __attribute__((ext_vector_type(4)));

// dequant 4 bytes (one u32) -> two f16 pairs in /256 domain (no bias add).
// bytes (0,2)->alo, (1,3)->ahi. code c -> f16 bits (c<<7), value/256 exact
// for c>=8; c==0 -> exactly 0.
__device__ __forceinline__ void fp8x4_acc(unsigned w, h2& alo, h2& ahi)
{
    const unsigned lo = (w << 7) & 0x3f803f80u;
    const unsigned hi = (w >> 1) & 0x3f803f80u;
    alo += __builtin_bit_cast(h2, lo);
    ahi += __builtin_bit_cast(h2, hi);
}

// quantize float (>=0) -> byte. Consumer reconstructs value/256 then x256.
__device__ __forceinline__ unsigned char q8(float v)
{
    const unsigned short hb = __builtin_bit_cast(unsigned short, (_Float16)v);
    int t = ((hb + 0x40) >> 7) - 64;
    t = t < 0 ? 0 : (t > 126 ? 126 : t);
    return (unsigned char)t;
}

// --- w1t transpose-cvt (must precede fused1: gemm1 reads w1t there)
__global__ __launch_bounds__(256) void cvt_w1(
    const float* __restrict__ w1, _Float16* __restrict__ w1t)
{
    const int k = blockIdx.x, n = threadIdx.x;
    w1t[n * 256 + k] = (_Float16)w1[k * 256 + n];
}

// --- MFMA fp16 GEMM body (R10 v3): out = q8(relu(A @ Wt^T + bias)).
//     Byte-swizzled fp8 output: feature j of each 4-group -> byte {0,2,1,3}.
template <bool AF32>
__device__ __forceinline__ void gemm_body(
    char* smemRaw, const void* __restrict__ Av, const _Float16* __restrict__ Wt,
    const float* __restrict__ bias, unsigned char* __restrict__ out, int M, int bid)
{
    constexpr int K = 256;
    constexpr int LDB = 264;                // conflict-free
    _Float16* Bs = (_Float16*)smemRaw;      // 128*264 f16 = 67584B

    const int tid  = threadIdx.x;
    const int wave = tid >> 6;
    const int lane = tid & 63;
    const int quad = lane >> 4;
    const int l16  = lane & 15;
    const int row0 = bid * 128;

    const int gr0 = min(row0 + wave * 32 + l16,      M - 1);
    const int gr1 = min(row0 + wave * 32 + 16 + l16, M - 1);

    half8 aReg[2][8];
    if constexpr (AF32) {
        const float* A = (const float*)Av;
        #pragma unroll
        for (int mi = 0; mi < 2; ++mi) {
            const int gr = mi ? gr1 : gr0;
            #pragma unroll
            for (int kk = 0; kk < 8; ++kk) {
                const float4 u0 = *(const float4*)(A + (size_t)gr * K + kk * 32 + quad * 8);
                const float4 u1 = *(const float4*)(A + (size_t)gr * K + kk * 32 + quad * 8 + 4);
                aReg[mi][kk][0] = (_Float16)u0.x; aReg[mi][kk][1] = (_Float16)u0.y;
                aReg[mi][kk][2] = (_Float16)u0.z; aReg[mi][kk][3] = (_Float16)u0.w;
                aReg[mi][kk][4] = (_Float16)u1.x; aReg[mi][kk][5] = (_Float16)u1.y;
                aReg[mi][kk][6] = (_Float16)u1.z; aReg[mi][kk][7] = (_Float16)u1.w;
            }
        }
    } else {
        const _Float16* A = (const _Float16*)Av;
        #pragma unroll
        for (int mi = 0; mi < 2; ++mi) {
            const int gr = mi ? gr1 : gr0;
            #pragma unroll
            for (int kk = 0; kk < 8; ++kk)
                aReg[mi][kk] = *(const half8*)(A + (size_t)gr * K + kk * 32 + quad * 8);
        }
    }

    f32x4 acc[2][16] = {};

    #pragma unroll
    for (int hf = 0; hf < 2; ++hf) {
        if (hf) __syncthreads();
        #pragma unroll
        for (int c = 0; c < 16; ++c) {
            const int idx = c * 256 + tid;
            const int n   = idx >> 5;
            const int ko  = (idx & 31) * 8;
            *(half8*)&Bs[n * LDB + ko] =
                *(const half8*)(Wt + (size_t)(hf * 128 + n) * K + ko);
        }
        __syncthreads();

        #pragma unroll
        for (int kk = 0; kk < 8; ++kk) {
            #pragma unroll
            for (int ni = 0; ni < 8; ++ni) {
                const half8 bf = *(const half8*)&Bs[(ni * 16 + l16) * LDB + kk * 32 + quad * 8];
                acc[0][hf * 8 + ni] = __builtin_amdgcn_mfma_f32_16x16x32_f16(
                    aReg[0][kk], bf, acc[0][hf * 8 + ni], 0, 0, 0);
                acc[1][hf * 8 + ni] = __builtin_amdgcn_mfma_f32_16x16x32_f16(
                    aReg[1][kk], bf, acc[1][hf * 8 + ni], 0, 0, 0);
            }
        }
    }

    // epilogue: C/D layout col=lane&15, row=quad*4+reg; quantize + swizzle
    #pragma unroll
    for (int ci = 0; ci < 16; ++ci) {
        const int col  = ci * 16 + l16;
        const int bcol = (col & ~3) | (((col & 1) << 1) | ((col >> 1) & 1));
        const float b = bias[col];
        #pragma unroll
        for (int mi = 0; mi < 2; ++mi) {
            #pragma unroll
            for (int r = 0; r < 4; ++r) {
                const int grow = row0 + wave * 32 + mi * 16 + quad * 4 + r;
                if (grow < M) {
                    const float v = fmaxf(acc[mi][ci][r] + b, 0.f);
                    out[(size_t)grow * K + bcol] = q8(v);
                }
            }
        }
    }
}

// --- bucket scatter body: self-count chunk, reserve fixed-region space via
//     global atomicAdd on gcur, LDS-reorder, emit contiguous runs.
__device__ __forceinline__ void scatter_body(
    char* smemRaw, const int* __restrict__ src, const int* __restrict__ dst,
    int* __restrict__ gcur, int* __restrict__ packed, int E, int chunk, int kblk)
{
    int* lcnt   = (int*)smemRaw;         // 256
    int* loff   = lcnt + 256;            // 256
    int* cursor = loff + 256;            // 256
    int* gbase  = cursor + 256;          // 256
    int* segSum = gbase + 256;           // 16 (4 used)
    int* ldsOut = segSum + 16;           // MAXCHUNK

    const int tid  = threadIdx.x;
    const int wave = tid >> 6;
    const int lane = tid & 63;
    const int e0 = kblk * chunk;
    const int e1 = min(e0 + chunk, E);

    lcnt[tid] = 0;
    __syncthreads();
    for (int i = e0 + tid; i < e1; i += 256)
        atomicAdd(&lcnt[dst[i] >> 8], 1);
    __syncthreads();

    const int v = lcnt[tid];
    {
        int s = v;
        #pragma unroll
        for (int off = 1; off < 64; off <<= 1) {
            const int t = __shfl_up(s, off, 64);
            if (lane >= off) s += t;
        }
        loff[tid] = s - v;
        if (lane == 63) segSum[wave] = s;
    }
    __syncthreads();
    if (tid == 0) {
        int c = 0;
        #pragma unroll
        for (int w = 0; w < 4; ++w) { const int t = segSum[w]; segSum[w] = c; c += t; }
    }
    __syncthreads();
    loff[tid] += segSum[wave];
    gbase[tid] = atomicAdd(&gcur[tid], v);
    cursor[tid] = 0;
    __syncthreads();

    for (int i = e0 + tid; i < e1; i += 256) {
        const int d = dst[i];
        const int b = d >> 8;
        const int pos = atomicAdd(&cursor[b], 1);
        ldsOut[loff[b] + pos] = (src[i] << 8) | (d & 255);
    }
    __syncthreads();

    for (int b = wave; b < NBUCK; b += 4) {
        const int cnt = lcnt[b];
        const int gb  = b * CAP + gbase[b];
        const int lb  = loff[b];
        for (int j = lane; j < cnt; j += 64)
            packed[gb + j] = ldsOut[lb + j];
    }
}

// --- fused: gemm1 (layer 1, A=f32 x) ∪ bucket scatter ∪ w2t/wfcT cvt
__global__ __launch_bounds__(256, 2) void fused1(
    const float* __restrict__ x, const _Float16* __restrict__ w1t,
    const float* __restrict__ b1, unsigned char* __restrict__ bufM, int M,
    const int* __restrict__ edge_src, const int* __restrict__ edge_dst,
    int* __restrict__ gcur, int* __restrict__ packed, int E, int chunk,
    const float* __restrict__ w2, _Float16* __restrict__ w2t,
    const float* __restrict__ wfc, _Float16* __restrict__ wfcT,
    int gemmBlocks)
{
    __shared__ __align__(16) char smem[128 * 264 * 2];   // 67584B
    const int bid = blockIdx.x;
    if (bid < gemmBlocks) {
        gemm_body<true>(smem, x, w1t, b1, bufM, M, bid);
    } else if (bid < gemmBlocks + NB) {
        scatter_body(smem, edge_src, edge_dst, gcur, packed, E, chunk,
                     bid - gemmBlocks);
    } else {
        const int r = bid - gemmBlocks - NB;   // [0,512)
        const int n = threadIdx.x;
        if (r < 256) {
            w2t[n * 256 + r] = (_Float16)w2[r * 256 + n];
        } else {
            const int k = r - 256;
            if (n < 48)
                wfcT[n * 256 + k] = (n < C_DIM) ? (_Float16)wfc[k * C_DIM + n]
                                                : (_Float16)0.f;
        }
    }
}

// --- standalone layer-2 GEMM (fp16 in, q8 out)
__global__ __launch_bounds__(256, 2) void gemm_l2(
    const _Float16* __restrict__ A, const _Float16* __restrict__ Wt,
    const float* __restrict__ bias, unsigned char* __restrict__ out, int M)
{
    __shared__ __align__(16) char smem[128 * 264 * 2];
    gemm_body<false>(smem, A, Wt, bias, out, M, blockIdx.x);
}

// --- bucket -> CSR: redundant per-block scan of bucket counts gives compact
//     csr base; then per-bucket node histogram -> rowptr/rowEnd + csr_src.
__global__ __launch_bounds__(256) void bucket_to_csr(
    const int* __restrict__ packed, const int* __restrict__ gcur,
    int* __restrict__ rowptr, int* __restrict__ rowEnd,
    int* __restrict__ csr_src, int N)
{
    __shared__ int lcnt[NBUCK], loff[NBUCK], cursor[NBUCK], gscan[NBUCK];
    __shared__ int segSum[4];
    const int tid  = threadIdx.x;
    const int wave = tid >> 6;
    const int lane = tid & 63;
    const int b    = blockIdx.x;
    const int nodeBase = b * NBUCK;
    if (nodeBase >= N) return;

    {
        const int v = gcur[tid];
        int s = v;
        #pragma unroll
        for (int off = 1; off < 64; off <<= 1) {
            const int t = __shfl_up(s, off, 64);
            if (lane >= off) s += t;
        }
        if (lane == 63) segSum[wave] = s;
        gscan[tid] = s - v;
    }
    __syncthreads();
    if (tid == 0) {
        int c = 0;
        #pragma unroll
        for (int w = 0; w < 4; ++w) { const int t = segSum[w]; segSum[w] = c; c += t; }
    }
    __syncthreads();
    gscan[tid] += segSum[wave];
    __syncthreads();
    const int cbase = gscan[b];
    const int cnt   = gcur[b];
    const int pbeg  = b * CAP;

    lcnt[tid] = 0;
    __syncthreads();

    for (int e = tid; e < cnt; e += 256)
        atomicAdd(&lcnt[packed[pbeg + e] & 255], 1);
    __syncthreads();

    {
        const int v = lcnt[tid];
        int s = v;
        #pragma unroll
        for (int off = 1; off < 64; off <<= 1) {
            const int t = __shfl_up(s, off, 64);
            if (lane >= off) s += t;
        }
        loff[tid] = s - v;
        if (lane == 63) segSum[wave] = s;
    }
    __syncthreads();
    if (tid == 0) {
        int c = 0;
        #pragma unroll
        for (int w = 0; w < 4; ++w) { const int t = segSum[w]; segSum[w] = c; c += t; }
    }
    __syncthreads();
    loff[tid] += segSum[wave];
    cursor[tid] = 0;
    __syncthreads();

    if (nodeBase + tid < N) {
        rowptr[nodeBase + tid] = cbase + loff[tid];
        rowEnd[nodeBase + tid] = cbase + loff[tid] + lcnt[tid];
    }
    __syncthreads();

    for (int e = tid; e < cnt; e += 256) {
        const int p = packed[pbeg + e];
        const int node = p & 255;
        const int pos = atomicAdd(&cursor[node], 1);
        csr_src[cbase + loff[node] + pos] = p >> 8;
    }
}

// --- shared gather core: accumulate q8 rows (256B each) into 4 f16 pairs
//     (/256 domain). 32 lanes/row, lane rl holds features rl*8..rl*8+7.
__device__ __forceinline__ void gather_core(
    const unsigned char* __restrict__ msgS, const int* __restrict__ csr_src,
    int beg, int end, int rl, int gsrc,
    h2& a0, h2& a1, h2& a2, h2& a3)
{
    int sv = (beg + rl < end) ? csr_src[beg + rl] : 0;
    for (int e0 = beg; e0 < end; e0 += 32) {
        const int n = min(32, end - e0);
        int svn = 0;
        if (e0 + 32 < end)
            svn = (e0 + 32 + rl < end) ? csr_src[e0 + 32 + rl] : 0;
        int j = 0;
        for (; j + 16 <= n; j += 16) {
            int s[16];
            #pragma unroll
            for (int u = 0; u < 16; ++u) s[u] = __shfl(sv, gsrc + j + u, 64);
            uint2 v[16];
            #pragma unroll
            for (int u = 0; u < 16; ++u)
                v[u] = *(const uint2*)(msgS + (size_t)s[u] * F_DIM);
            #pragma unroll
            for (int u = 0; u < 16; ++u) {
                fp8x4_acc(v[u].x, a0, a1);
                fp8x4_acc(v[u].y, a2, a3);
            }
        }
        for (; j + 8 <= n; j += 8) {
            int s[8];
            #pragma unroll
            for (int u = 0; u < 8; ++u) s[u] = __shfl(sv, gsrc + j + u, 64);
            uint2 v[8];
            #pragma unroll
            for (int u = 0; u < 8; ++u)
                v[u] = *(const uint2*)(msgS + (size_t)s[u] * F_DIM);
            #pragma unroll
            for (int u = 0; u < 8; ++u) {
                fp8x4_acc(v[u].x, a0, a1);
                fp8x4_acc(v[u].y, a2, a3);
            }
        }
        for (; j < n; ++j) {
            const int s = __shfl(sv, gsrc + j, 64);
            const uint2 w = *(const uint2*)(msgS + (size_t)s * F_DIM);
            fp8x4_acc(w.x, a0, a1);
            fp8x4_acc(w.y, a2, a3);
        }
        sv = svn;
    }
}

// --- conv aggregate (layer 1): h[row] = 256 * sum_{/256 domain} -> f16
__global__ __launch_bounds__(512) void csr_gather_fp8(
    const unsigned char* __restrict__ msg, const int* __restrict__ rowptr,
    const int* __restrict__ rowEnd, const int* __restrict__ csr_src,
    _Float16* __restrict__ h, int N)
{
    const int tid  = threadIdx.x;
    const int wave = tid >> 6;
    const int lane = tid & 63;
    const int g    = lane >> 5;
    const int rl   = lane & 31;
    const int gsrc = lane & 32;
    const int row  = (blockIdx.x * 8 + wave) * 2 + g;
    if (row >= N) return;

    const unsigned char* msgS = msg + rl * 8;
    h2 a0 = {}, a1 = {}, a2 = {}, a3 = {};
    const uint2 w = *(const uint2*)(msgS + (size_t)row * F_DIM);   // self
    fp8x4_acc(w.x, a0, a1);
    fp8x4_acc(w.y, a2, a3);

    gather_core(msgS, csr_src, rowptr[row], rowEnd[row], rl, gsrc, a0, a1, a2, a3);

    const h2 s2 = {(_Float16)256.f, (_Float16)256.f};
    a0 *= s2; a1 *= s2; a2 *= s2; a3 *= s2;
    half8 o;
    o[0] = a0[0]; o[1] = a0[1]; o[2] = a1[0]; o[3] = a1[1];
    o[4] = a2[0]; o[5] = a2[1]; o[6] = a3[0]; o[7] = a3[1];
    *(half8*)(h + (size_t)row * F_DIM + rl * 8) = o;
}

// --- conv aggregate (layer 2) fused with FC: block = 16 rows = one MFMA
//     m-tile; h tile in LDS fp16; 3 waves compute 16x40 logits via MFMA.
__global__ __launch_bounds__(512) void gather_fc(
    const unsigned char* __restrict__ msg, const int* __restrict__ rowptr,
    const int* __restrict__ rowEnd, const int* __restrict__ csr_src,
    const _Float16* __restrict__ wfcT, const float* __restrict__ bfc,
    float* __restrict__ logits, int N)
{
    constexpr int LDB = 264;
    __shared__ _Float16 Bs[48 * LDB];   // wfcT tile
    __shared__ _Float16 hs[16 * LDB];   // h tile (16 rows)

    const int tid  = threadIdx.x;
    const int wave = tid >> 6;
    const int lane = tid & 63;
    const int g    = lane >> 5;
    const int rl   = lane & 31;
    const int gsrc = lane & 32;
    const int row  = blockIdx.x * 16 + wave * 2 + g;

    // stage wfcT (48x256) early; overlaps with gather latency
    #pragma unroll
    for (int c = 0; c < 3; ++c) {
        const int idx = c * 512 + tid;
        const int n   = idx >> 5;
        const int ko  = (idx & 31) * 8;
        *(half8*)&Bs[n * LDB + ko] = *(const half8*)(wfcT + (size_t)n * 256 + ko);
    }

    if (row < N) {
        const unsigned char* msgS = msg + rl * 8;
        h2 a0 = {}, a1 = {}, a2 = {}, a3 = {};
        const uint2 w = *(const uint2*)(msgS + (size_t)row * F_DIM);   // self
        fp8x4_acc(w.x, a0, a1);
        fp8x4_acc(w.y, a2, a3);

        gather_core(msgS, csr_src, rowptr[row], rowEnd[row], rl, gsrc,
                    a0, a1, a2, a3);

        const h2 s2 = {(_Float16)256.f, (_Float16)256.f};
        a0 *= s2; a1 *= s2; a2 *= s2; a3 *= s2;
        half8 o;
        o[0] = a0[0]; o[1] = a0[1]; o[2] = a1[0]; o[3] = a1[1];
        o[4] = a2[0]; o[5] = a2[1]; o[6] = a3[0]; o[7] = a3[1];
        *(half8*)&hs[(wave * 2 + g) * LDB + rl * 8] = o;
    }
    __syncthreads();

    // FC: logits[16x40] = hs @ Bs^T + bfc; waves 0..2 each own 16 cols
    if (wave < 3) {
        const int quad = lane >> 4;
        const int l16  = lane & 15;
        const int ni   = wave;
        f32x4 acc = {};
        #pragma unroll
        for (int kk = 0; kk < 8; ++kk) {
            const half8 af = *(const half8*)&hs[l16 * LDB + kk * 32 + quad * 8];
            const half8 bf = *(const half8*)&Bs[(ni * 16 + l16) * LDB + kk * 32 + quad * 8];
            acc = __builtin_amdgcn_mfma_f32_16x16x32_f16(af, bf, acc, 0, 0, 0);
        }
        const int col = ni * 16 + l16;
        if (col < C_DIM) {
            const float b = bfc[col];
            #pragma unroll
            for (int r = 0; r < 4; ++r) {
                const int grow = blockIdx.x * 16 + quad * 4 + r;
                if (grow < N)
                    logits[(size_t)grow * C_DIM + col] = acc[r] + b;
            }
        }
    }
}

// --- sparse PvT: out[prow[i]] += pval[i] * logits[pcol[i]], wave/nnz
__global__ __launch_bounds__(256) void pvt_scatter(
    const float* __restrict__ logits, const int* __restrict__ prow,
    const int* __restrict__ pcol, const float* __restrict__ pval,
    float* __restrict__ out, int nnz)
{
    const int i    = (blockIdx.x * 256 + threadIdx.x) >> 6;
    const int lane = threadIdx.x & 63;
    if (i >= nnz || lane >= C_DIM) return;
    const int r = prow[i];
    const int c = pcol[i];
    const float v = pval[i];
    atomicAdd(out + (size_t)r * C_DIM + lane, v * logits[(size_t)c * C_DIM + lane]);
}

// --- row-wise log_softmax in place, wave/row (lanes 0..39 active)
__global__ __launch_bounds__(256) void log_softmax40(float* __restrict__ out, int M)
{
    const int row  = (blockIdx.x * 256 + threadIdx.x) >> 6;
    const int lane = threadIdx.x & 63;
    if (row >= M) return;
    const float v = (lane < C_DIM) ? out[(size_t)row * C_DIM + lane] : -INFINITY;
    float m = v;
    #pragma unroll
    for (int off = 32; off >= 1; off >>= 1)
        m = fmaxf(m, __shfl_xor(m, off, 64));
    float e = (lane < C_DIM) ? expf(v - m) : 0.f;
    float s = e;
    #pragma unroll
    for (int off = 32; off >= 1; off >>= 1)
        s += __shfl_xor(s, off, 64);
    if (lane < C_DIM)
        out[(size_t)row * C_DIM + lane] = v - m - logf(s);
}

extern "C" void kernel_launch(void* const* d_in, const int* in_sizes, int n_in,
                              void* d_out, int out_size, void* d_ws, size_t ws_size,
                              hipStream_t stream)
{
    const float* x        = (const float*)d_in[0];
    const int*   edge_src = (const int*)d_in[1];
    const int*   edge_dst = (const int*)d_in[2];
    const int*   pvt_row  = (const int*)d_in[3];
    const int*   pvt_col  = (const int*)d_in[4];
    const float* pvt_val  = (const float*)d_in[5];
    const float* w1       = (const float*)d_in[6];
    const float* b1       = (const float*)d_in[7];
    const float* w2       = (const float*)d_in[8];
    const float* b2       = (const float*)d_in[9];
    const float* wfc      = (const float*)d_in[10];
    const float* bfc      = (const float*)d_in[11];

    const int N   = in_sizes[0] / F_DIM;   // 50000
    const int E   = in_sizes[1];           // 1600000
    const int NNZ = in_sizes[3];           // 50000

    float* out = (float*)d_out;

    // workspace layout
    const size_t nodeElems = (size_t)N * F_DIM;
    _Float16* w1t     = (_Float16*)d_ws;              // 256*256 fp16
    _Float16* w2t     = w1t + 65536;                  // 256*256 fp16
    _Float16* wfcT    = w2t + 65536;                  // 48*256 fp16
    unsigned char* bufM = (unsigned char*)(wfcT + 48 * 256); // msg, N*256 q8
    _Float16* bufH    = (_Float16*)(bufM + nodeElems);       // h, N*256 fp16
    float*    logits  = (float*)(bufH + nodeElems);   // N x 40 f32
    int*      gcur    = (int*)(logits + (size_t)N * C_DIM); // 256 bucket counts
    int*      rowptr  = gcur + 256;                   // N
    int*      rowEnd  = rowptr + N + 8;               // N
    int*      csr_src = rowEnd + N + 8;               // E
    int*      packed  = (int*)bufH;                   // alias: dead until gather1

    const int chunk = (E + NB - 1) / NB;              // 6250, <= MAXCHUNK

    const int gemmBlocks  = (N + 127) / 128;          // 391
    const int rowBlocks   = (N + 3) / 4;
    const int gatherBlocks= (N + 15) / 16;            // 16 rows per 512-blk
    const int nnzBlocks   = (NNZ + 3) / 4;

    hipMemsetAsync(gcur, 0, 256 * sizeof(int), stream);
    hipMemsetAsync(d_out, 0, (size_t)N * C_DIM * sizeof(float), stream);

    // w1t cvt (gemm1 consumes it inside fused1)
    cvt_w1<<<256, 256, 0, stream>>>(w1, w1t);

    // === fused: gemm1 ∪ bucket scatter ∪ w2t/wfcT cvt ===
    fused1<<<gemmBlocks + NB + 512, 256, 0, stream>>>(
        x, w1t, b1, bufM, N, edge_src, edge_dst, gcur, packed, E, chunk,
        w2, w2t, wfc, wfcT, gemmBlocks);

    // === bucket -> CSR (compact bases computed per block) ===
    bucket_to_csr<<<NBUCK, 256, 0, stream>>>(packed, gcur,
                                             rowptr, rowEnd, csr_src, N);

    // === layer 1 aggregate (q8 msg) ===
    csr_gather_fp8<<<gatherBlocks, 512, 0, stream>>>(bufM, rowptr, rowEnd,
                                                     csr_src, bufH, N);

    // === layer 2 GEMM (fp16 h -> q8 msg) ===
    gemm_l2<<<gemmBlocks, 256, 0, stream>>>(bufH, w2t, b2, bufM, N);

    // === layer 2 aggregate + FC fused ===
    gather_fc<<<gatherBlocks, 512, 0, stream>>>(bufM, rowptr, rowEnd, csr_src,
                                                wfcT, bfc, logits, N);

    // === PvT scatter into d_out, then log_softmax ===
    pvt_scatter<<<nnzBlocks, 256, 0, stream>>>(logits, pvt_row, pvt_col, pvt_val, out, NNZ);
    log_softmax40<<<rowBlocks, 256, 0, stream>>>(out, N);
}

// Round 7
// 355.739 us; speedup vs baseline: 1.0930x; 1.0930x over previous
//
#include <hip/hip_runtime.h>
#include <hip/hip_bf16.h>
#include <math.h>

// ---------------------------------------------------------------------------
// MPNN node classifier.
// R19: packed GEMM epilogue. R18 showed fused1 at 76us with MfmaUtil 0.48%,
// VALUBusy 1.3% — pure stall; epilogue was 128 scattered byte-stores/lane.
// Redefine msg byte position of feature f as g(f)=swz(t(f)), t=16-transpose
// (involution), swz={0,2,1,3}: a lane's 16 accumulator cols now land at 16
// consecutive bytes -> 8 uint4 stores/lane, coalesced (quarter-wave = one
// 256B row). Gathers are position-blind; h output carries pure-t order, so
// w2t/wfcT cvt index K by t(q). Layer-1 x/w1t untouched. Rest = R18 (388us).
// ---------------------------------------------------------------------------

#define F_DIM 256   // F_IN == H == 256
#define C_DIM 40
#define NBUCK 256   // coarse buckets: dst >> 8
#define NB    256   // scatter chunks
#define MAXCHUNK 6400
#define CAP   16384 // fixed packed region per bucket (mean 8192, sigma~90)

typedef _Float16 half8 __attribute__((ext_vector_type(8)));
typedef _Float16 h2    __attribute__((ext_vector_type(2)));
typedef float    f32x4 __attribute__((ext_vector_type(4)));

// dequant 4 bytes (one u32) -> two f16 pairs in /256 domain (no bias add).
// bytes (0,2)->alo, (1,3)->ahi. code c -> f16 bits (c<<7), value/256 exact
// for c>=8; c==0 -> exactly 0.
__device__ __forceinline__ void fp8x4_acc(unsigned w, h2& alo, h2& ahi)
{
    const unsigned lo = (w << 7) & 0x3f803f80u;
    const unsigned hi = (w >> 1) & 0x3f803f80u;
    alo += __builtin_bit_cast(h2, lo);
    ahi += __builtin_bit_cast(h2, hi);
}

// quantize float (>=0) -> byte code (value/256 reconstruction domain)
__device__ __forceinline__ unsigned q8(float v)
{
    const unsigned short hb = __builtin_bit_cast(unsigned short, (_Float16)v);
    int t = ((hb + 0x40) >> 7) - 64;
    t = t < 0 ? 0 : (t > 126 ? 126 : t);
    return (unsigned)t;
}

// --- w1t transpose-cvt (must precede fused1: gemm1 reads w1t there)
__global__ __launch_bounds__(256) void cvt_w1(
    const float* __restrict__ w1, _Float16* __restrict__ w1t)
{
    const int k = blockIdx.x, n = threadIdx.x;
    w1t[n * 256 + k] = (_Float16)w1[k * 256 + n];
}

// --- MFMA fp16 GEMM body: out = q8(relu(A @ Wt^T + bias)) in g-permuted
//     byte layout: position p holds feature f with p = swz(t(f)).
//     Epilogue: per (mi,r) one uint4 store at out[grow*256 + l16*16].
template <bool AF32>
__device__ __forceinline__ void gemm_body(
    char* smemRaw, const void* __restrict__ Av, const _Float16* __restrict__ Wt,
    const float* __restrict__ bias, unsigned char* __restrict__ out, int M, int bid)
{
    constexpr int K = 256;
    constexpr int LDB = 264;                // conflict-free
    _Float16* Bs = (_Float16*)smemRaw;      // 128*264 f16 = 67584B

    const int tid  = threadIdx.x;
    const int wave = tid >> 6;
    const int lane = tid & 63;
    const int quad = lane >> 4;
    const int l16  = lane & 15;
    const int row0 = bid * 128;

    const int gr0 = min(row0 + wave * 32 + l16,      M - 1);
    const int gr1 = min(row0 + wave * 32 + 16 + l16, M - 1);

    half8 aReg[2][8];
    if constexpr (AF32) {
        const float* A = (const float*)Av;
        #pragma unroll
        for (int mi = 0; mi < 2; ++mi) {
            const int gr = mi ? gr1 : gr0;
            #pragma unroll
            for (int kk = 0; kk < 8; ++kk) {
                const float4 u0 = *(const float4*)(A + (size_t)gr * K + kk * 32 + quad * 8);
                const float4 u1 = *(const float4*)(A + (size_t)gr * K + kk * 32 + quad * 8 + 4);
                aReg[mi][kk][0] = (_Float16)u0.x; aReg[mi][kk][1] = (_Float16)u0.y;
                aReg[mi][kk][2] = (_Float16)u0.z; aReg[mi][kk][3] = (_Float16)u0.w;
                aReg[mi][kk][4] = (_Float16)u1.x; aReg[mi][kk][5] = (_Float16)u1.y;
                aReg[mi][kk][6] = (_Float16)u1.z; aReg[mi][kk][7] = (_Float16)u1.w;
            }
        }
    } else {
        const _Float16* A = (const _Float16*)Av;
        #pragma unroll
        for (int mi = 0; mi < 2; ++mi) {
            const int gr = mi ? gr1 : gr0;
            #pragma unroll
            for (int kk = 0; kk < 8; ++kk)
                aReg[mi][kk] = *(const half8*)(A + (size_t)gr * K + kk * 32 + quad * 8);
        }
    }

    f32x4 acc[2][16] = {};

    #pragma unroll
    for (int hf = 0; hf < 2; ++hf) {
        if (hf) __syncthreads();
        #pragma unroll
        for (int c = 0; c < 16; ++c) {
            const int idx = c * 256 + tid;
            const int n   = idx >> 5;
            const int ko  = (idx & 31) * 8;
            *(half8*)&Bs[n * LDB + ko] =
                *(const half8*)(Wt + (size_t)(hf * 128 + n) * K + ko);
        }
        __syncthreads();

        #pragma unroll
        for (int kk = 0; kk < 8; ++kk) {
            #pragma unroll
            for (int ni = 0; ni < 8; ++ni) {
                const half8 bf = *(const half8*)&Bs[(ni * 16 + l16) * LDB + kk * 32 + quad * 8];
                acc[0][hf * 8 + ni] = __builtin_amdgcn_mfma_f32_16x16x32_f16(
                    aReg[0][kk], bf, acc[0][hf * 8 + ni], 0, 0, 0);
                acc[1][hf * 8 + ni] = __builtin_amdgcn_mfma_f32_16x16x32_f16(
                    aReg[1][kk], bf, acc[1][hf * 8 + ni], 0, 0, 0);
            }
        }
    }

    // bias per owned col (col = ci*16 + l16)
    float bv[16];
    #pragma unroll
    for (int ci = 0; ci < 16; ++ci) bv[ci] = bias[ci * 16 + l16];

    // epilogue: pack 16 cols -> 16 bytes -> one uint4 per (mi,r).
    // u32 w holds bytes {acc[4w+0], acc[4w+2], acc[4w+1], acc[4w+3]}.
    #pragma unroll
    for (int mi = 0; mi < 2; ++mi) {
        #pragma unroll
        for (int r = 0; r < 4; ++r) {
            const int grow = row0 + wave * 32 + mi * 16 + quad * 4 + r;
            if (grow < M) {
                uint4 pk;
                unsigned pw[4];
                #pragma unroll
                for (int w = 0; w < 4; ++w) {
                    const int c0 = w * 4;
                    const unsigned b0 = q8(fmaxf(acc[mi][c0 + 0][r] + bv[c0 + 0], 0.f));
                    const unsigned b1 = q8(fmaxf(acc[mi][c0 + 2][r] + bv[c0 + 2], 0.f));
                    const unsigned b2 = q8(fmaxf(acc[mi][c0 + 1][r] + bv[c0 + 1], 0.f));
                    const unsigned b3 = q8(fmaxf(acc[mi][c0 + 3][r] + bv[c0 + 3], 0.f));
                    pw[w] = b0 | (b1 << 8) | (b2 << 16) | (b3 << 24);
                }
                pk.x = pw[0]; pk.y = pw[1]; pk.z = pw[2]; pk.w = pw[3];
                *(uint4*)(out + (size_t)grow * 256 + l16 * 16) = pk;
            }
        }
    }
}

// --- bucket scatter body: self-count chunk, reserve fixed-region space via
//     global atomicAdd on gcur, LDS-reorder, emit contiguous runs.
__device__ __forceinline__ void scatter_body(
    char* smemRaw, const int* __restrict__ src, const int* __restrict__ dst,
    int* __restrict__ gcur, int* __restrict__ packed, int E, int chunk, int kblk)
{
    int* lcnt   = (int*)smemRaw;         // 256
    int* loff   = lcnt + 256;            // 256
    int* cursor = loff + 256;            // 256
    int* gbase  = cursor + 256;          // 256
    int* segSum = gbase + 256;           // 16 (4 used)
    int* ldsOut = segSum + 16;           // MAXCHUNK

    const int tid  = threadIdx.x;
    const int wave = tid >> 6;
    const int lane = tid & 63;
    const int e0 = kblk * chunk;
    const int e1 = min(e0 + chunk, E);

    lcnt[tid] = 0;
    __syncthreads();
    for (int i = e0 + tid; i < e1; i += 256)
        atomicAdd(&lcnt[dst[i] >> 8], 1);
    __syncthreads();

    const int v = lcnt[tid];
    {
        int s = v;
        #pragma unroll
        for (int off = 1; off < 64; off <<= 1) {
            const int t = __shfl_up(s, off, 64);
            if (lane >= off) s += t;
        }
        loff[tid] = s - v;
        if (lane == 63) segSum[wave] = s;
    }
    __syncthreads();
    if (tid == 0) {
        int c = 0;
        #pragma unroll
        for (int w = 0; w < 4; ++w) { const int t = segSum[w]; segSum[w] = c; c += t; }
    }
    __syncthreads();
    loff[tid] += segSum[wave];
    gbase[tid] = atomicAdd(&gcur[tid], v);
    cursor[tid] = 0;
    __syncthreads();

    for (int i = e0 + tid; i < e1; i += 256) {
        const int d = dst[i];
        const int b = d >> 8;
        const int pos = atomicAdd(&cursor[b], 1);
        ldsOut[loff[b] + pos] = (src[i] << 8) | (d & 255);
    }
    __syncthreads();

    for (int b = wave; b < NBUCK; b += 4) {
        const int cnt = lcnt[b];
        const int gb  = b * CAP + gbase[b];
        const int lb  = loff[b];
        for (int j = lane; j < cnt; j += 64)
            packed[gb + j] = ldsOut[lb + j];
    }
}

// --- fused: gemm1 (layer 1, A=f32 x) ∪ bucket scatter ∪ w2t/wfcT cvt
//     (w2t/wfcT K-index permuted by t: position q holds feature t(q))
__global__ __launch_bounds__(256, 2) void fused1(
    const float* __restrict__ x, const _Float16* __restrict__ w1t,
    const float* __restrict__ b1, unsigned char* __restrict__ bufM, int M,
    const int* __restrict__ edge_src, const int* __restrict__ edge_dst,
    int* __restrict__ gcur, int* __restrict__ packed, int E, int chunk,
    const float* __restrict__ w2, _Float16* __restrict__ w2t,
    const float* __restrict__ wfc, _Float16* __restrict__ wfcT,
    int gemmBlocks)
{
    __shared__ __align__(16) char smem[128 * 264 * 2];   // 67584B
    const int bid = blockIdx.x;
    if (bid < gemmBlocks) {
        gemm_body<true>(smem, x, w1t, b1, bufM, M, bid);
    } else if (bid < gemmBlocks + NB) {
        scatter_body(smem, edge_src, edge_dst, gcur, packed, E, chunk,
                     bid - gemmBlocks);
    } else {
        const int r = bid - gemmBlocks - NB;   // [0,512)
        const int n = threadIdx.x;
        if (r < 256) {
            const int tr = ((r & 15) << 4) | (r >> 4);   // t(r), involution
            w2t[n * 256 + r] = (_Float16)w2[tr * 256 + n];
        } else {
            const int k  = r - 256;
            const int tk = ((k & 15) << 4) | (k >> 4);
            if (n < 48)
                wfcT[n * 256 + k] = (n < C_DIM) ? (_Float16)wfc[tk * C_DIM + n]
                                                : (_Float16)0.f;
        }
    }
}

// --- standalone layer-2 GEMM (fp16 in, q8 out)
__global__ __launch_bounds__(256, 2) void gemm_l2(
    const _Float16* __restrict__ A, const _Float16* __restrict__ Wt,
    const float* __restrict__ bias, unsigned char* __restrict__ out, int M)
{
    __shared__ __align__(16) char smem[128 * 264 * 2];
    gemm_body<false>(smem, A, Wt, bias, out, M, blockIdx.x);
}

// --- bucket -> CSR: redundant per-block scan of bucket counts gives compact
//     csr base; then per-bucket node histogram -> rowptr/rowEnd + csr_src.
__global__ __launch_bounds__(256) void bucket_to_csr(
    const int* __restrict__ packed, const int* __restrict__ gcur,
    int* __restrict__ rowptr, int* __restrict__ rowEnd,
    int* __restrict__ csr_src, int N)
{
    __shared__ int lcnt[NBUCK], loff[NBUCK], cursor[NBUCK], gscan[NBUCK];
    __shared__ int segSum[4];
    const int tid  = threadIdx.x;
    const int wave = tid >> 6;
    const int lane = tid & 63;
    const int b    = blockIdx.x;
    const int nodeBase = b * NBUCK;
    if (nodeBase >= N) return;

    {
        const int v = gcur[tid];
        int s = v;
        #pragma unroll
        for (int off = 1; off < 64; off <<= 1) {
            const int t = __shfl_up(s, off, 64);
            if (lane >= off) s += t;
        }
        if (lane == 63) segSum[wave] = s;
        gscan[tid] = s - v;
    }
    __syncthreads();
    if (tid == 0) {
        int c = 0;
        #pragma unroll
        for (int w = 0; w < 4; ++w) { const int t = segSum[w]; segSum[w] = c; c += t; }
    }
    __syncthreads();
    gscan[tid] += segSum[wave];
    __syncthreads();
    const int cbase = gscan[b];
    const int cnt   = gcur[b];
    const int pbeg  = b * CAP;

    lcnt[tid] = 0;
    __syncthreads();

    for (int e = tid; e < cnt; e += 256)
        atomicAdd(&lcnt[packed[pbeg + e] & 255], 1);
    __syncthreads();

    {
        const int v = lcnt[tid];
        int s = v;
        #pragma unroll
        for (int off = 1; off < 64; off <<= 1) {
            const int t = __shfl_up(s, off, 64);
            if (lane >= off) s += t;
        }
        loff[tid] = s - v;
        if (lane == 63) segSum[wave] = s;
    }
    __syncthreads();
    if (tid == 0) {
        int c = 0;
        #pragma unroll
        for (int w = 0; w < 4; ++w) { const int t = segSum[w]; segSum[w] = c; c += t; }
    }
    __syncthreads();
    loff[tid] += segSum[wave];
    cursor[tid] = 0;
    __syncthreads();

    if (nodeBase + tid < N) {
        rowptr[nodeBase + tid] = cbase + loff[tid];
        rowEnd[nodeBase + tid] = cbase + loff[tid] + lcnt[tid];
    }
    __syncthreads();

    for (int e = tid; e < cnt; e += 256) {
        const int p = packed[pbeg + e];
        const int node = p & 255;
        const int pos = atomicAdd(&cursor[node], 1);
        csr_src[cbase + loff[node] + pos] = p >> 8;
    }
}

// --- shared gather core: accumulate q8 rows (256B each) into 4 f16 pairs
//     (/256 domain). 32 lanes/row, lane rl holds bytes rl*8..rl*8+7.
__device__ __forceinline__ void gather_core(
    const unsigned char* __restrict__ msgS, const int* __restrict__ csr_src,
    int beg, int end, int rl, int gsrc,
    h2& a0, h2& a1, h2& a2, h2& a3)
{
    int sv = (beg + rl < end) ? csr_src[beg + rl] : 0;
    for (int e0 = beg; e0 < end; e0 += 32) {
        const int n = min(32, end - e0);
        int svn = 0;
        if (e0 + 32 < end)
            svn = (e0 + 32 + rl < end) ? csr_src[e0 + 32 + rl] : 0;
        int j = 0;
        for (; j + 16 <= n; j += 16) {
            int s[16];
            #pragma unroll
            for (int u = 0; u < 16; ++u) s[u] = __shfl(sv, gsrc + j + u, 64);
            uint2 v[16];
            #pragma unroll
            for (int u = 0; u < 16; ++u)
                v[u] = *(const uint2*)(msgS + (size_t)s[u] * F_DIM);
            #pragma unroll
            for (int u = 0; u < 16; ++u) {
                fp8x4_acc(v[u].x, a0, a1);
                fp8x4_acc(v[u].y, a2, a3);
            }
        }
        for (; j + 8 <= n; j += 8) {
            int s[8];
            #pragma unroll
            for (int u = 0; u < 8; ++u) s[u] = __shfl(sv, gsrc + j + u, 64);
            uint2 v[8];
            #pragma unroll
            for (int u = 0; u < 8; ++u)
                v[u] = *(const uint2*)(msgS + (size_t)s[u] * F_DIM);
            #pragma unroll
            for (int u = 0; u < 8; ++u) {
                fp8x4_acc(v[u].x, a0, a1);
                fp8x4_acc(v[u].y, a2, a3);
            }
        }
        for (; j < n; ++j) {
            const int s = __shfl(sv, gsrc + j, 64);
            const uint2 w = *(const uint2*)(msgS + (size_t)s * F_DIM);
            fp8x4_acc(w.x, a0, a1);
            fp8x4_acc(w.y, a2, a3);
        }
        sv = svn;
    }
}

// --- conv aggregate (layer 1): h[row] = 256 * sum_{/256 domain} -> f16
__global__ __launch_bounds__(512) void csr_gather_fp8(
    const unsigned char* __restrict__ msg, const int* __restrict__ rowptr,
    const int* __restrict__ rowEnd, const int* __restrict__ csr_src,
    _Float16* __restrict__ h, int N)
{
    const int tid  = threadIdx.x;
    const int wave = tid >> 6;
    const int lane = tid & 63;
    const int g    = lane >> 5;
    const int rl   = lane & 31;
    const int gsrc = lane & 32;
    const int row  = (blockIdx.x * 8 + wave) * 2 + g;
    if (row >= N) return;

    const unsigned char* msgS = msg + rl * 8;
    h2 a0 = {}, a1 = {}, a2 = {}, a3 = {};
    const uint2 w = *(const uint2*)(msgS + (size_t)row * F_DIM);   // self
    fp8x4_acc(w.x, a0, a1);
    fp8x4_acc(w.y, a2, a3);

    gather_core(msgS, csr_src, rowptr[row], rowEnd[row], rl, gsrc, a0, a1, a2, a3);

    const h2 s2 = {(_Float16)256.f, (_Float16)256.f};
    a0 *= s2; a1 *= s2; a2 *= s2; a3 *= s2;
    half8 o;
    o[0] = a0[0]; o[1] = a0[1]; o[2] = a1[0]; o[3] = a1[1];
    o[4] = a2[0]; o[5] = a2[1]; o[6] = a3[0]; o[7] = a3[1];
    *(half8*)(h + (size_t)row * F_DIM + rl * 8) = o;
}

// --- conv aggregate (layer 2) fused with FC: block = 16 rows = one MFMA
//     m-tile; h tile in LDS fp16; 3 waves compute 16x40 logits via MFMA.
__global__ __launch_bounds__(512) void gather_fc(
    const unsigned char* __restrict__ msg, const int* __restrict__ rowptr,
    const int* __restrict__ rowEnd, const int* __restrict__ csr_src,
    const _Float16* __restrict__ wfcT, const float* __restrict__ bfc,
    float* __restrict__ logits, int N)
{
    constexpr int LDB = 264;
    __shared__ _Float16 Bs[48 * LDB];   // wfcT tile
    __shared__ _Float16 hs[16 * LDB];   // h tile (16 rows)

    const int tid  = threadIdx.x;
    const int wave = tid >> 6;
    const int lane = tid & 63;
    const int g    = lane >> 5;
    const int rl   = lane & 31;
    const int gsrc = lane & 32;
    const int row  = blockIdx.x * 16 + wave * 2 + g;

    // stage wfcT (48x256) early; overlaps with gather latency
    #pragma unroll
    for (int c = 0; c < 3; ++c) {
        const int idx = c * 512 + tid;
        const int n   = idx >> 5;
        const int ko  = (idx & 31) * 8;
        *(half8*)&Bs[n * LDB + ko] = *(const half8*)(wfcT + (size_t)n * 256 + ko);
    }

    if (row < N) {
        const unsigned char* msgS = msg + rl * 8;
        h2 a0 = {}, a1 = {}, a2 = {}, a3 = {};
        const uint2 w = *(const uint2*)(msgS + (size_t)row * F_DIM);   // self
        fp8x4_acc(w.x, a0, a1);
        fp8x4_acc(w.y, a2, a3);

        gather_core(msgS, csr_src, rowptr[row], rowEnd[row], rl, gsrc,
                    a0, a1, a2, a3);

        const h2 s2 = {(_Float16)256.f, (_Float16)256.f};
        a0 *= s2; a1 *= s2; a2 *= s2; a3 *= s2;
        half8 o;
        o[0] = a0[0]; o[1] = a0[1]; o[2] = a1[0]; o[3] = a1[1];
        o[4] = a2[0]; o[5] = a2[1]; o[6] = a3[0]; o[7] = a3[1];
        *(half8*)&hs[(wave * 2 + g) * LDB + rl * 8] = o;
    }
    __syncthreads();

    // FC: logits[16x40] = hs @ Bs^T + bfc; waves 0..2 each own 16 cols
    if (wave < 3) {
        const int quad = lane >> 4;
        const int l16  = lane & 15;
        const int ni   = wave;
        f32x4 acc = {};
        #pragma unroll
        for (int kk = 0; kk < 8; ++kk) {
            const half8 af = *(const half8*)&hs[l16 * LDB + kk * 32 + quad * 8];
            const half8 bf = *(const half8*)&Bs[(ni * 16 + l16) * LDB + kk * 32 + quad * 8];
            acc = __builtin_amdgcn_mfma_f32_16x16x32_f16(af, bf, acc, 0, 0, 0);
        }
        const int col = ni * 16 + l16;
        if (col < C_DIM) {
            const float b = bfc[col];
            #pragma unroll
            for (int r = 0; r < 4; ++r) {
                const int grow = blockIdx.x * 16 + quad * 4 + r;
                if (grow < N)
                    logits[(size_t)grow * C_DIM + col] = acc[r] + b;
            }
        }
    }
}

// --- sparse PvT: out[prow[i]] += pval[i] * logits[pcol[i]], wave/nnz
__global__ __launch_bounds__(256) void pvt_scatter(
    const float* __restrict__ logits, const int* __restrict__ prow,
    const int* __restrict__ pcol, const float* __restrict__ pval,
    float* __restrict__ out, int nnz)
{
    const int i    = (blockIdx.x * 256 + threadIdx.x) >> 6;
    const int lane = threadIdx.x & 63;
    if (i >= nnz || lane >= C_DIM) return;
    const int r = prow[i];
    const int c = pcol[i];
    const float v = pval[i];
    atomicAdd(out + (size_t)r * C_DIM + lane, v * logits[(size_t)c * C_DIM + lane]);
}

// --- row-wise log_softmax in place, wave/row (lanes 0..39 active)
__global__ __launch_bounds__(256) void log_softmax40(float* __restrict__ out, int M)
{
    const int row  = (blockIdx.x * 256 + threadIdx.x) >> 6;
    const int lane = threadIdx.x & 63;
    if (row >= M) return;
    const float v = (lane < C_DIM) ? out[(size_t)row * C_DIM + lane] : -INFINITY;
    float m = v;
    #pragma unroll
    for (int off = 32; off >= 1; off >>= 1)
        m = fmaxf(m, __shfl_xor(m, off, 64));
    float e = (lane < C_DIM) ? expf(v - m) : 0.f;
    float s = e;
    #pragma unroll
    for (int off = 32; off >= 1; off >>= 1)
        s += __shfl_xor(s, off, 64);
    if (lane < C_DIM)
        out[(size_t)row * C_DIM + lane] = v - m - logf(s);
}

extern "C" void kernel_launch(void* const* d_in, const int* in_sizes, int n_in,
                              void* d_out, int out_size, void* d_ws, size_t ws_size,
                              hipStream_t stream)
{
    const float* x        = (const float*)d_in[0];
    const int*   edge_src = (const int*)d_in[1];
    const int*   edge_dst = (const int*)d_in[2];
    const int*   pvt_row  = (const int*)d_in[3];
    const int*   pvt_col  = (const int*)d_in[4];
    const float* pvt_val  = (const float*)d_in[5];
    const float* w1       = (const float*)d_in[6];
    const float* b1       = (const float*)d_in[7];
    const float* w2       = (const float*)d_in[8];
    const float* b2       = (const float*)d_in[9];
    const float* wfc      = (const float*)d_in[10];
    const float* bfc      = (const float*)d_in[11];

    const int N   = in_sizes[0] / F_DIM;   // 50000
    const int E   = in_sizes[1];           // 1600000
    const int NNZ = in_sizes[3];           // 50000

    float* out = (float*)d_out;

    // workspace layout
    const size_t nodeElems = (size_t)N * F_DIM;
    _Float16* w1t     = (_Float16*)d_ws;              // 256*256 fp16
    _Float16* w2t     = w1t + 65536;                  // 256*256 fp16
    _Float16* wfcT    = w2t + 65536;                  // 48*256 fp16
    unsigned char* bufM = (unsigned char*)(wfcT + 48 * 256); // msg, N*256 q8
    _Float16* bufH    = (_Float16*)(bufM + nodeElems);       // h, N*256 fp16
    float*    logits  = (float*)(bufH + nodeElems);   // N x 40 f32
    int*      gcur    = (int*)(logits + (size_t)N * C_DIM); // 256 bucket counts
    int*      rowptr  = gcur + 256;                   // N
    int*      rowEnd  = rowptr + N + 8;               // N
    int*      csr_src = rowEnd + N + 8;               // E
    int*      packed  = (int*)bufH;                   // alias: dead until gather1

    const int chunk = (E + NB - 1) / NB;              // 6250, <= MAXCHUNK

    const int gemmBlocks  = (N + 127) / 128;          // 391
    const int rowBlocks   = (N + 3) / 4;
    const int gatherBlocks= (N + 15) / 16;            // 16 rows per 512-blk
    const int nnzBlocks   = (NNZ + 3) / 4;

    hipMemsetAsync(gcur, 0, 256 * sizeof(int), stream);
    hipMemsetAsync(d_out, 0, (size_t)N * C_DIM * sizeof(float), stream);

    // w1t cvt (gemm1 consumes it inside fused1)
    cvt_w1<<<256, 256, 0, stream>>>(w1, w1t);

    // === fused: gemm1 ∪ bucket scatter ∪ w2t/wfcT cvt ===
    fused1<<<gemmBlocks + NB + 512, 256, 0, stream>>>(
        x, w1t, b1, bufM, N, edge_src, edge_dst, gcur, packed, E, chunk,
        w2, w2t, wfc, wfcT, gemmBlocks);

    // === bucket -> CSR (compact bases computed per block) ===
    bucket_to_csr<<<NBUCK, 256, 0, stream>>>(packed, gcur,
                                             rowptr, rowEnd, csr_src, N);

    // === layer 1 aggregate (q8 msg) ===
    csr_gather_fp8<<<gatherBlocks, 512, 0, stream>>>(bufM, rowptr, rowEnd,
                                                     csr_src, bufH, N);

    // === layer 2 GEMM (fp16 h -> q8 msg) ===
    gemm_l2<<<gemmBlocks, 256, 0, stream>>>(bufH, w2t, b2, bufM, N);

    // === layer 2 aggregate + FC fused ===
    gather_fc<<<gatherBlocks, 512, 0, stream>>>(bufM, rowptr, rowEnd, csr_src,
                                                wfcT, bfc, logits, N);

    // === PvT scatter into d_out, then log_softmax ===
    pvt_scatter<<<nnzBlocks, 256, 0, stream>>>(logits, pvt_row, pvt_col, pvt_val, out, NNZ);
    log_softmax40<<<rowBlocks, 256, 0, stream>>>(out, N);
}